// Round 4
// baseline (321.964 us; speedup 1.0000x reference)
//
#include <hip/hip_runtime.h>
#include <stdint.h>

typedef unsigned short u16;
typedef __bf16 bfx8 __attribute__((ext_vector_type(8)));
typedef short  sx4  __attribute__((ext_vector_type(4)));
typedef float  fx4  __attribute__((ext_vector_type(4)));
typedef float  fx16 __attribute__((ext_vector_type(16)));
typedef u16    ux8  __attribute__((ext_vector_type(8)));
typedef u16    ux4  __attribute__((ext_vector_type(4)));
typedef float  flt4 __attribute__((ext_vector_type(4)));

#define DIM   1536
#define NH    12
#define HD    128
#define BATCH 2
#define SEQ   2048
#define MTOK  (BATCH*SEQ)
#define EPSV  1e-6f
#define SCALE 0.08838834764831845f
#define NX    (MTOK*DIM)
#define NW    (DIM*DIM)

__device__ __forceinline__ u16 f2bf(float x){
  union { float f; uint32_t u; } v; v.f = x;
  return (u16)((v.u + 0x7FFFu + ((v.u >> 16) & 1u)) >> 16);
}
__device__ __forceinline__ float bf2f(u16 h){
  union { uint32_t u; float f; } v; v.u = ((uint32_t)h) << 16; return v.f;
}
__device__ __forceinline__ void gl_lds16(const void* g, void* l){
  __builtin_amdgcn_global_load_lds((const __attribute__((address_space(1))) void*)g,
                                   (__attribute__((address_space(3))) void*)l, 16, 0, 0);
}
__device__ __forceinline__ fx4 fzero(){ fx4 z = {0.f,0.f,0.f,0.f}; return z; }

// ---------------- convert fp32 -> bf16 (x + 4 weights) ----------------
__global__ __launch_bounds__(256)
void convert_k(const float* __restrict__ x, const float* __restrict__ wq,
               const float* __restrict__ wk, const float* __restrict__ wv,
               const float* __restrict__ wo,
               u16* __restrict__ xb, u16* __restrict__ wqb, u16* __restrict__ wkb,
               u16* __restrict__ wvb, u16* __restrict__ wob)
{
  const long i4 = (long)(blockIdx.x * 256 + threadIdx.x) * 4;
  const float* src; u16* dst; long off;
  if (i4 < NX){ src = x; dst = xb; off = i4; }
  else {
    long j = i4 - NX;
    if      (j < (long)NW)   { src = wq; dst = wqb; off = j; }
    else if (j < 2L*NW)      { src = wk; dst = wkb; off = j - NW; }
    else if (j < 3L*NW)      { src = wv; dst = wvb; off = j - 2L*NW; }
    else                     { src = wo; dst = wob; off = j - 3L*NW; }
  }
  flt4 v = *(const flt4*)(src + off);
  ux4 o;
  o[0] = f2bf(v[0]); o[1] = f2bf(v[1]); o[2] = f2bf(v[2]); o[3] = f2bf(v[3]);
  *(ux4*)(dst + off) = o;
}

// ---------------- GEMM core: C = A * W^T + bias, double-buffered LDS ----------------
#define BM 128
#define BN 128
#define BK 64
#define NKIT (DIM/BK)

// MODE 0: bf16 out + row sumsq atomics; MODE 1: V -> transposed vt out; MODE 2: f32 out
template<int MODE>
__device__ __forceinline__ void gemm_core(char* smem,
                                          const u16* __restrict__ A, const u16* __restrict__ W,
                                          const float* __restrict__ bias,
                                          u16* __restrict__ outb, float* __restrict__ outf,
                                          float* __restrict__ sumsq, u16* __restrict__ vtout)
{
  const int t = threadIdx.x;
  const int lane = t & 63;
  const int wid = t >> 6;
  const int wm = wid >> 1, wn = wid & 1;
  const int quad = lane >> 4, l15 = lane & 15;

  // XCD-aware swizzle: the 12 blocks sharing an A-stripe land on one XCD
  const int lin = blockIdx.y * 12 + blockIdx.x;   // dispatch-linear within z
  const int r   = lin >> 3;                        // 0..47
  const int m0  = ((lin & 7) + 8 * (r / 12)) * BM;
  const int n0  = (r % 12) * BN;

  fx4 acc[4][4];
  #pragma unroll
  for (int i = 0; i < 4; ++i)
    #pragma unroll
    for (int j = 0; j < 4; ++j) acc[i][j] = fzero();

  const int ri  = t >> 3;   // 0..31
  const int sg0 = t & 7;

  // stage K-block kb into buffer p (p*32768: A 16K | B 16K)
  auto stage = [&](int kb, int p){
    const int k0 = kb * BK;
    char* base = smem + p * 32768;
    #pragma unroll
    for (int s = 0; s < 4; ++s){
      const int row = s*32 + ri;
      const int sa = sg0 ^ (row & 7);
      gl_lds16(A + (size_t)(m0+row)*DIM + k0 + sa*8, base + s*4096 + t*16);
      gl_lds16(W + (size_t)(n0+row)*DIM + k0 + sa*8, base + 16384 + s*4096 + t*16);
    }
  };

  stage(0, 0);
  for (int kb = 0; kb < NKIT; ++kb){
    char* cur = smem + (kb & 1) * 32768;
    __syncthreads();                       // drains stage(kb); frees buf (kb+1)&1
    if (kb + 1 < NKIT) stage(kb + 1, (kb + 1) & 1);
    #pragma unroll
    for (int kk = 0; kk < 2; ++kk){
      bfx8 af[4], bw[4];
      #pragma unroll
      for (int i = 0; i < 4; ++i){
        const int rA = wm*64 + i*16 + l15;
        af[i] = *(const bfx8*)(cur + rA*128 + (((kk*4 + quad) ^ (rA & 7)) * 16));
        const int rB = wn*64 + i*16 + l15;
        bw[i] = *(const bfx8*)(cur + 16384 + rB*128 + (((kk*4 + quad) ^ (rB & 7)) * 16));
      }
      #pragma unroll
      for (int i = 0; i < 4; ++i)
        #pragma unroll
        for (int j = 0; j < 4; ++j)
          acc[i][j] = __builtin_amdgcn_mfma_f32_16x16x32_bf16(af[i], bw[j], acc[i][j], 0, 0, 0);
    }
  }

  float bvals[4];
  #pragma unroll
  for (int j = 0; j < 4; ++j) bvals[j] = bias[n0 + wn*64 + j*16 + l15];

  if (MODE == 1){
    // V epilogue: bf16 transpose via XOR-swizzled LDS tile, then coalesced vt write.
    u16* T = (u16*)smem;   // 32 KB at buf0 (compute(last) read buf1; buf0 is free)
    #pragma unroll
    for (int i = 0; i < 4; ++i){
      const int row0  = wm*64 + i*16 + quad*4;
      const int chunk = row0 >> 3;
      const int half  = quad & 1;
      #pragma unroll
      for (int j = 0; j < 4; ++j){
        const int col = wn*64 + j*16 + l15;
        ux4 w4;
        #pragma unroll
        for (int rr = 0; rr < 4; ++rr) w4[rr] = f2bf(acc[i][j][rr] + bvals[j]);
        *(ux4*)((char*)T + col*256 + ((chunk ^ (col & 15)) << 4) + half*8) = w4;
      }
    }
    __syncthreads();
    const int b   = m0 >> 11;       // SEQ = 2048
    const int m0l = m0 & (SEQ - 1);
    const int cr  = t & 15;         // row chunk (8 toks)
    #pragma unroll
    for (int s = 0; s < 8; ++s){
      const int cl = s*16 + (t >> 4);
      const ux8 v = *(const ux8*)((char*)T + cl*256 + ((cr ^ (cl & 15)) << 4));
      const int cg = n0 + cl;
      const int hh = cg >> 7, dd = cg & (HD - 1);
      *(ux8*)(vtout + (size_t)((b*NH + hh)*HD + dd)*SEQ + m0l + cr*8) = v;
    }
    return;
  }

  #pragma unroll
  for (int i = 0; i < 4; ++i){
    #pragma unroll
    for (int rr = 0; rr < 4; ++rr){
      const int grow = m0 + wm*64 + i*16 + quad*4 + rr;
      float s2 = 0.f;
      #pragma unroll
      for (int j = 0; j < 4; ++j){
        const int gcol = n0 + wn*64 + j*16 + l15;
        const float v = acc[i][j][rr] + bvals[j];
        if (MODE == 2) outf[(size_t)grow*DIM + gcol] = v;
        else           outb[(size_t)grow*DIM + gcol] = f2bf(v);
        s2 += v*v;
      }
      if (MODE == 0){
        s2 += __shfl_xor(s2, 1);
        s2 += __shfl_xor(s2, 2);
        s2 += __shfl_xor(s2, 4);
        s2 += __shfl_xor(s2, 8);
        if (l15 == 0) atomicAdd(&sumsq[grow], s2);
      }
    }
  }
}

__global__ __launch_bounds__(256)
void gemm_qkv_k(const u16* __restrict__ xb,
                const u16* __restrict__ wqb, const u16* __restrict__ wkb, const u16* __restrict__ wvb,
                const float* __restrict__ bq, const float* __restrict__ bk, const float* __restrict__ bv,
                u16* __restrict__ qraw, u16* __restrict__ kraw, u16* __restrict__ vt,
                float* __restrict__ ssq, float* __restrict__ ssk)
{
  __shared__ char smem[65536];
  const int z = blockIdx.z;
  if (z == 0)      gemm_core<0>(smem, xb, wqb, bq, qraw, nullptr, ssq, nullptr);
  else if (z == 1) gemm_core<0>(smem, xb, wkb, bk, kraw, nullptr, ssk, nullptr);
  else             gemm_core<1>(smem, xb, wvb, bv, nullptr, nullptr, nullptr, vt);
}

__global__ __launch_bounds__(256)
void gemm_out_k(const u16* __restrict__ attnb, const u16* __restrict__ wob,
                const float* __restrict__ bo, float* __restrict__ out)
{
  __shared__ char smem[65536];
  gemm_core<2>(smem, attnb, wob, bo, nullptr, out, nullptr, nullptr);
}

// ---------------- RMSNorm + RoPE (q and k); Q additionally pre-scaled by 1/sqrt(d) ----------------
__global__ __launch_bounds__(256)
void normrope_k(const u16* __restrict__ qraw, const u16* __restrict__ kraw,
                const float* __restrict__ ssq, const float* __restrict__ ssk,
                const float* __restrict__ gq, const float* __restrict__ gk,
                const float* __restrict__ freqs,
                u16* __restrict__ qbf, u16* __restrict__ kbf)
{
  const int row = blockIdx.x;
  const int isK = blockIdx.y;
  const u16* src   = isK ? kraw : qraw;
  const float* ss  = isK ? ssk  : ssq;
  const float* g   = isK ? gk   : gq;
  u16* dst         = isK ? kbf  : qbf;
  const int spos = row & (SEQ - 1);
  float rstd = rsqrtf(ss[row] * (1.0f/DIM) + EPSV);
  if (!isK) rstd *= SCALE;   // fold softmax scale into Q
  #pragma unroll
  for (int it = 0; it < 3; ++it){
    const int p = threadIdx.x + it*256;
    const int d = p*2;
    const int hd = d & (HD-1);
    const uint32_t two = *(const uint32_t*)(src + (size_t)row*DIM + d);
    const float y0 = bf2f((u16)(two & 0xFFFFu)) * rstd * g[d];
    const float y1 = bf2f((u16)(two >> 16))     * rstd * g[d+1];
    const float c  = freqs[spos*(2*HD) + hd];
    const float sn = freqs[spos*(2*HD) + HD + hd];
    const float o0 = y0*c - y1*sn;
    const float o1 = y1*c + y0*sn;
    *(uint32_t*)(dst + (size_t)row*DIM + d) = (uint32_t)f2bf(o0) | ((uint32_t)f2bf(o1) << 16);
  }
}

// ---------------- Flash attention (32x32 MFMA, software-pipelined staging) ----------------
// LDS: Kbuf0 [0,16K) | Kbuf1 [16K,32K) | Vbuf [32K,48K) | mlbuf [48K,48.5K)
// Pipeline per iter: barrier(b) -> issue V(kt)+K(kt+1) DMA -> QK^T+softmax (covers DMA latency)
// -> barrier(a, drains V) -> PV. K(kt) was drained by iter kt-1's barrier(a).
__global__ __launch_bounds__(256, 3)
void flash_k(const u16* __restrict__ qbf, const u16* __restrict__ kbf, const u16* __restrict__ vt,
             const int* __restrict__ seq_lens, u16* __restrict__ attnb)
{
  __shared__ char smem[50176];
  const int t = threadIdx.x;
  const int lane = t & 63;
  const int h = lane >> 5;          // half-wave
  const int l31 = lane & 31;
  const int wq = (t >> 6) & 1;
  const int wk = t >> 7;

  // XCD swizzle: 32 q-tiles of one (head,batch) pair on one XCD; 3 pairs/XCD
  const int u  = blockIdx.x;              // 0..767
  const int qt = (u >> 3) & 31;
  const int pr = (u & 7) + 8 * (u >> 8);  // 0..23
  const int hh = pr % 12;
  const int b  = pr / 12;

  const int q0 = qt * 64 + wq * 32;
  const int tokbase = b * SEQ;
  const int kvlen = min(seq_lens[b], SEQ);
  const int ntiles = (kvlen + 63) >> 6;

  // Q fragments in registers (B-operand layout: n=l31 -> query, k=h*8+j -> d)
  bfx8 qf[8];
  {
    const u16* qp = qbf + (size_t)(tokbase + q0 + l31)*DIM + hh*HD + h*8;
    #pragma unroll
    for (int c = 0; c < 8; ++c) qf[c] = *(const bfx8*)(qp + c*16);
  }

  fx16 o[4];
  #pragma unroll
  for (int dt = 0; dt < 4; ++dt)
    #pragma unroll
    for (int r = 0; r < 16; ++r) o[dt][r] = 0.f;
  float mrow = -1e30f, lrow = 0.f;

  const int kri = t >> 4, kseg = t & 15;
  const int vri = t >> 3, vseg = t & 7;
  const int krow = wk*32 + l31;

  // stage K(0) into Kbuf0
  #pragma unroll
  for (int s = 0; s < 4; ++s){
    const int row = s*16 + kri;
    const int sg = kseg ^ (row & 15);
    gl_lds16(kbf + (size_t)(tokbase + row)*DIM + hh*HD + sg*8, smem + s*4096 + t*16);
  }

  for (int kt = 0; kt < ntiles; ++kt){
    char* kbuf = smem + (kt & 1) * 16384;
    __syncthreads();   // (b): prev PV done -> Vbuf free; drains K(0) on kt=0

    { // issue V(kt) DMA
      #pragma unroll
      for (int s = 0; s < 4; ++s){
        const int row = s*32 + vri;
        const int sg = vseg ^ (row & 7);
        gl_lds16(vt + (size_t)((b*NH + hh)*HD + row)*SEQ + kt*64 + sg*8, smem + 32768 + s*4096 + t*16);
      }
    }
    if (kt + 1 < ntiles){ // issue K(kt+1) DMA into other K buffer
      char* knext = smem + ((kt + 1) & 1) * 16384;
      #pragma unroll
      for (int s = 0; s < 4; ++s){
        const int row = s*16 + kri;
        const int sg = kseg ^ (row & 15);
        gl_lds16(kbf + (size_t)(tokbase + (kt+1)*64 + row)*DIM + hh*HD + sg*8, knext + s*4096 + t*16);
      }
    }

    // S^T (32k x 32q) for this wave's key half — K(kt) already resident
    fx16 st;
    #pragma unroll
    for (int r = 0; r < 16; ++r) st[r] = 0.f;
    #pragma unroll
    for (int c = 0; c < 8; ++c){
      const bfx8 kf = *(const bfx8*)(kbuf + krow*256 + (((2*c + h) ^ (krow & 15)) << 4));
      st = __builtin_amdgcn_mfma_f32_32x32x16_bf16(kf, qf[c], st, 0, 0, 0);
    }

    if ((kt == ntiles - 1) && (kvlen & 63)){
      #pragma unroll
      for (int r = 0; r < 16; ++r){
        const int key = kt*64 + wk*32 + (r & 3) + 8*(r >> 2) + 4*h;
        if (key >= kvlen) st[r] = -1e30f;
      }
    }

    float tm = st[0];
    #pragma unroll
    for (int r = 1; r < 16; ++r) tm = fmaxf(tm, st[r]);
    tm = fmaxf(tm, __shfl_xor(tm, 32));
    if (__any(tm > mrow)){
      const float mnew = fmaxf(mrow, tm);
      const float alpha = __expf(mrow - mnew);
      lrow *= alpha;
      #pragma unroll
      for (int dt = 0; dt < 4; ++dt)
        #pragma unroll
        for (int r = 0; r < 16; ++r) o[dt][r] *= alpha;
      mrow = mnew;
    }

    uint32_t tt[16];
    float ps = 0.f;
    #pragma unroll
    for (int r = 0; r < 16; ++r){
      union { float f; uint32_t u; } e; e.f = __expf(st[r] - mrow);
      const uint32_t uu = e.u + 0x8000u;
      tt[r] = uu;
      union { uint32_t u; float f; } pm; pm.u = uu & 0xFFFF0000u;
      ps += pm.f;
    }
    ps += __shfl_xor(ps, 32);
    lrow += ps;

    sx4 pb[4];
    #pragma unroll
    for (int ks = 0; ks < 4; ++ks){
      union { uint32_t u[2]; sx4 s; } pk;
      pk.u[0] = __builtin_amdgcn_perm(tt[4*ks+1], tt[4*ks+0], 0x07060302u);
      pk.u[1] = __builtin_amdgcn_perm(tt[4*ks+3], tt[4*ks+2], 0x07060302u);
      pb[ks] = pk.s;
    }

    __syncthreads();   // (a): drains V(kt) DMA (K(kt+1) drains early — mostly overlapped)

    #pragma unroll
    for (int ks = 0; ks < 4; ++ks){
      #pragma unroll
      for (int dt = 0; dt < 4; ++dt){
        const int row = dt*32 + l31;
        const sx4 vf = *(const sx4*)(smem + 32768 + row*128 + ((((wk<<2) + ks) ^ (row & 7)) << 4) + (h << 3));
        o[dt] = __builtin_amdgcn_mfma_f32_32x32x8bf16_1k(vf, pb[ks], o[dt], 0, 0, 0);
      }
    }
  }

  // ---- epilogue: merge wk halves, normalize, store (XOR-swizzled LDS, conflict-free) ----
  __syncthreads();
  float* mlbuf = (float*)(smem + 49152);     // [wk][wq][2][32]
  if (h == 0){
    mlbuf[((wk*2 + wq)*2 + 0)*32 + l31] = mrow;
    mlbuf[((wk*2 + wq)*2 + 1)*32 + l31] = lrow;
  }
  __syncthreads();
  const float mo = mlbuf[(((wk^1)*2 + wq)*2 + 0)*32 + l31];
  const float lo = mlbuf[(((wk^1)*2 + wq)*2 + 1)*32 + l31];
  const float M  = fmaxf(mrow, mo);
  const float f  = __expf(mrow - M);
  const float L  = lrow * f + lo * __expf(mo - M);
  #pragma unroll
  for (int dt = 0; dt < 4; ++dt)
    #pragma unroll
    for (int r = 0; r < 16; ++r) o[dt][r] *= f;
  __syncthreads();

  // xbuf: [64 q][512B], fx4 slot at q*512 + ((d>>2 ^ (q&31))<<4)
  char* xbuf = smem;
  const int qrow = wq*32 + l31;
  if (wk == 1){
    #pragma unroll
    for (int dt = 0; dt < 4; ++dt)
      #pragma unroll
      for (int rq = 0; rq < 4; ++rq){
        const int d = dt*32 + 8*rq + 4*h;
        fx4 v4; v4[0]=o[dt][4*rq]; v4[1]=o[dt][4*rq+1]; v4[2]=o[dt][4*rq+2]; v4[3]=o[dt][4*rq+3];
        *(fx4*)(xbuf + qrow*512 + (((d >> 2) ^ (qrow & 31)) << 4)) = v4;
      }
  }
  __syncthreads();

  // Os: [64 q][256B], ux4 at q*256 + ((d>>3 ^ (q&15))<<4) + (d&4)*2
  char* Os = smem + 32768;
  if (wk == 0){
    const float invL = 1.0f / L;
    #pragma unroll
    for (int dt = 0; dt < 4; ++dt)
      #pragma unroll
      for (int rq = 0; rq < 4; ++rq){
        const int d = dt*32 + 8*rq + 4*h;
        const fx4 p4 = *(const fx4*)(xbuf + qrow*512 + (((d >> 2) ^ (qrow & 31)) << 4));
        ux4 b4;
        #pragma unroll
        for (int j = 0; j < 4; ++j) b4[j] = f2bf((o[dt][4*rq + j] + p4[j]) * invL);
        *(ux4*)(Os + qrow*256 + (((d >> 3) ^ (qrow & 15)) << 4) + (d & 4)*2) = b4;
      }
  }
  __syncthreads();
  {
    const int ri = t >> 4, seg = t & 15;
    #pragma unroll
    for (int s = 0; s < 4; ++s){
      const int row = s*16 + ri;
      const ux8 val = *(const ux8*)(Os + row*256 + ((seg ^ (row & 15)) << 4));
      *(ux8*)(attnb + (size_t)(tokbase + qt*64 + row)*DIM + hh*HD + seg*8) = val;
    }
  }
}

// ---------------- launch ----------------
extern "C" void kernel_launch(void* const* d_in, const int* in_sizes, int n_in,
                              void* d_out, int out_size, void* d_ws, size_t ws_size,
                              hipStream_t stream)
{
  (void)in_sizes; (void)n_in; (void)out_size; (void)ws_size;
  const float* x      = (const float*)d_in[0];
  const float* wq     = (const float*)d_in[1];
  const float* bq     = (const float*)d_in[2];
  const float* wk     = (const float*)d_in[3];
  const float* bk     = (const float*)d_in[4];
  const float* wv     = (const float*)d_in[5];
  const float* bv     = (const float*)d_in[6];
  const float* wo     = (const float*)d_in[7];
  const float* bo     = (const float*)d_in[8];
  const float* gq     = (const float*)d_in[9];
  const float* gk     = (const float*)d_in[10];
  const float* freqs  = (const float*)d_in[11];
  const int*   seqls  = (const int*)d_in[12];

  char* ws = (char*)d_ws;
  u16* xb   = (u16*)(ws + 0);
  u16* wqb  = (u16*)(ws + 12582912);
  u16* wkb  = (u16*)(ws + 17301504);
  u16* wvb  = (u16*)(ws + 22020096);
  u16* wob  = (u16*)(ws + 26738688);
  u16* qraw = (u16*)(ws + 31457280);   // reused as attnb after normrope
  u16* kraw = (u16*)(ws + 44040192);
  u16* vt   = (u16*)(ws + 56623104);   // V directly in [b,h,d,tok] from gemm epilogue
  u16* qbf  = (u16*)(ws + 69206016);
  u16* kbf  = (u16*)(ws + 81788928);
  float* ssq = (float*)(ws + 94371840);
  float* ssk = (float*)(ws + 94388224);
  u16* attnb = qraw;

  (void)hipMemsetAsync(ssq, 0, 32768, stream);   // zero both sumsq buffers (contiguous)

  convert_k   <<<15360, 256, 0, stream>>>(x, wq, wk, wv, wo, xb, wqb, wkb, wvb, wob);
  gemm_qkv_k  <<<dim3(12, 32, 3), 256, 0, stream>>>(xb, wqb, wkb, wvb, bq, bk, bv,
                                                    qraw, kraw, vt, ssq, ssk);
  normrope_k  <<<dim3(4096, 2), 256, 0, stream>>>(qraw, kraw, ssq, ssk, gq, gk, freqs, qbf, kbf);
  flash_k     <<<dim3(768), 256, 0, stream>>>(qbf, kbf, vt, seqls, attnb);
  gemm_out_k  <<<dim3(12, 32), 256, 0, stream>>>(attnb, wob, bo, (float*)d_out);
}